// Round 5
// baseline (375.726 us; speedup 1.0000x reference)
//
#include <hip/hip_runtime.h>

#define S 2048
#define D 768
#define NH 12
#define HD 64
#define TD (3 * D)

typedef __bf16 bf16_t;
typedef __bf16 v8bf __attribute__((ext_vector_type(8)));
typedef __bf16 v4bf __attribute__((ext_vector_type(4)));
typedef float v4f __attribute__((ext_vector_type(4)));

// ---------- reductions ----------
__device__ __forceinline__ float wave_reduce_sum(float v) {
#pragma unroll
    for (int o = 32; o > 0; o >>= 1) v += __shfl_down(v, o, 64);
    return v;
}
__device__ float block_reduce_sum(float v) {
    __shared__ float t4[4];
    int lane = threadIdx.x & 63, wid = threadIdx.x >> 6;
    v = wave_reduce_sum(v);
    __syncthreads();
    if (lane == 0) t4[wid] = v;
    __syncthreads();
    return t4[0] + t4[1] + t4[2] + t4[3];
}

// ---------- fused residual-add + LayerNorm (ln0: two fp32 inputs) ----------
__global__ __launch_bounds__(256) void add_ln(const float* __restrict__ A, const float* __restrict__ Bv,
                                              const float* __restrict__ g, const float* __restrict__ be,
                                              bf16_t* __restrict__ out) {
    int row = blockIdx.x, t = threadIdx.x;
    const float* a = A + (size_t)row * D;
    const float* b = Bv + (size_t)row * D;
    float x[3];
    float s = 0.f;
#pragma unroll
    for (int i = 0; i < 3; ++i) { int c = t + 256 * i; x[i] = a[c] + b[c]; s += x[i]; }
    float mean = block_reduce_sum(s) * (1.0f / D);
    float vs = 0.f;
#pragma unroll
    for (int i = 0; i < 3; ++i) { float d = x[i] - mean; vs += d * d; }
    float var = block_reduce_sum(vs) * (1.0f / D);
    float rstd = rsqrtf(var + 1e-5f);
#pragma unroll
    for (int i = 0; i < 3; ++i) {
        int c = t + 256 * i;
        out[(size_t)row * D + c] = (bf16_t)((x[i] - mean) * rstd * g[c] + be[c]);
    }
}

// ---------- single-input LayerNorm ----------
template <typename TO>
__global__ __launch_bounds__(256) void ln_only(const bf16_t* __restrict__ X,
                                               const float* __restrict__ g, const float* __restrict__ be,
                                               TO* __restrict__ out) {
    int row = blockIdx.x, t = threadIdx.x;
    const bf16_t* a = X + (size_t)row * D;
    float x[3];
    float s = 0.f;
#pragma unroll
    for (int i = 0; i < 3; ++i) { int c = t + 256 * i; x[i] = (float)a[c]; s += x[i]; }
    float mean = block_reduce_sum(s) * (1.0f / D);
    float vs = 0.f;
#pragma unroll
    for (int i = 0; i < 3; ++i) { float d = x[i] - mean; vs += d * d; }
    float var = block_reduce_sum(vs) * (1.0f / D);
    float rstd = rsqrtf(var + 1e-5f);
#pragma unroll
    for (int i = 0; i < 3; ++i) {
        int c = t + 256 * i;
        out[(size_t)row * D + c] = (TO)((x[i] - mean) * rstd * g[c] + be[c]);
    }
}

// ---------- fused fp32 -> bf16 conversion of all 4 weight matrices ----------
#define NW0 (TD * D / 4)
#define NW1 (D * D / 4)
#define NW2 ((D / 2) * D / 4)
#define NW3 (D * (D / 2) / 4)
__global__ __launch_bounds__(256) void cvt_all(const float* __restrict__ s0, const float* __restrict__ s1,
                                               const float* __restrict__ s2, const float* __restrict__ s3,
                                               bf16_t* __restrict__ d0, bf16_t* __restrict__ d1,
                                               bf16_t* __restrict__ d2, bf16_t* __restrict__ d3) {
    int i = blockIdx.x * 256 + threadIdx.x;
    const float* sp; bf16_t* dp;
    if (i < NW0) { sp = s0; dp = d0; }
    else if (i < NW0 + NW1) { sp = s1; dp = d1; i -= NW0; }
    else if (i < NW0 + NW1 + NW2) { sp = s2; dp = d2; i -= NW0 + NW1; }
    else if (i < NW0 + NW1 + NW2 + NW3) { sp = s3; dp = d3; i -= NW0 + NW1 + NW2; }
    else return;
    float4 v = ((const float4*)sp)[i];
    v4bf o = {(bf16_t)v.x, (bf16_t)v.y, (bf16_t)v.z, (bf16_t)v.w};
    *(v4bf*)(dp + (size_t)i * 4) = o;
}

// ---------- MFMA GEMM: C[M,N] = act(A[M,K] @ B[N,K]^T + bias[N]) [+ Rsd] ----------
// TM x TN tile, BK=32, 256 threads as 2x2 waves. global_load_lds width-16 staging;
// chunk->LDS mapping is wave-uniform-base + lane*16 by construction. Chunk passes
// are wave-uniform ((TM+TN)*4 is a multiple of 64).
#define GBK 32

template <int TM, int TN, int RELU, bool RESID>
__global__ __launch_bounds__(256) void gemm_mfma(const bf16_t* __restrict__ A, const bf16_t* __restrict__ B,
                                                 const float* __restrict__ bias,
                                                 const bf16_t* __restrict__ Rsd, bf16_t* __restrict__ C,
                                                 int M, int N, int K) {
    constexpr int CA = TM * 4;                 // A chunks (16 B each, 4 per row)
    constexpr int CHUNKS = (TM + TN) * 4;
    constexpr int P = (CHUNKS + 255) / 256;
    constexpr int MI = TM / 32, NI = TN / 32;
    __shared__ bf16_t As[TM * GBK];
    __shared__ bf16_t Bs[TN * GBK];
    const int t = threadIdx.x;
    const int lane = t & 63, wave = t >> 6;
    const int wr = (wave >> 1) * (TM / 2), wc = (wave & 1) * (TN / 2);
    const int m0 = blockIdx.y * TM, n0 = blockIdx.x * TN;
    const int lm = lane & 15, q = lane >> 4;

    const bf16_t* gsrc[P];
    bf16_t* ldst[P];
    bool act[P];
#pragma unroll
    for (int p = 0; p < P; ++p) {
        int c = t + 256 * p;
        act[p] = (c < CHUNKS);
        int cc = (c < CA) ? c : c - CA;
        int row = cc >> 2, col = (cc & 3) * 8;
        if (c < CA) { gsrc[p] = A + (size_t)(m0 + row) * K + col; ldst[p] = As + cc * 8; }
        else        { gsrc[p] = B + (size_t)(n0 + row) * K + col; ldst[p] = Bs + cc * 8; }
    }

    v4f acc[MI][NI] = {};

    for (int k0 = 0; k0 < K; k0 += GBK) {
#pragma unroll
        for (int p = 0; p < P; ++p)
            if (act[p])
                __builtin_amdgcn_global_load_lds((const __attribute__((address_space(1))) void*)(gsrc[p] + k0),
                                                 (__attribute__((address_space(3))) void*)ldst[p], 16, 0, 0);
        __syncthreads();  // drains vmcnt -> staged data visible

        v8bf af[MI], bfr[NI];
#pragma unroll
        for (int i = 0; i < MI; ++i) af[i] = *(const v8bf*)(As + (wr + i * 16 + lm) * GBK + q * 8);
#pragma unroll
        for (int j = 0; j < NI; ++j) bfr[j] = *(const v8bf*)(Bs + (wc + j * 16 + lm) * GBK + q * 8);
#pragma unroll
        for (int i = 0; i < MI; ++i)
#pragma unroll
            for (int j = 0; j < NI; ++j)
                acc[i][j] = __builtin_amdgcn_mfma_f32_16x16x32_bf16(af[i], bfr[j], acc[i][j], 0, 0, 0);
        __syncthreads();
    }

    // D mapping (verified m89/m91): row = quad*4 + reg, col = lane&15
#pragma unroll
    for (int i = 0; i < MI; ++i)
#pragma unroll
        for (int j = 0; j < NI; ++j) {
            int col = n0 + wc + j * 16 + lm;
            float bs = bias[col];
#pragma unroll
            for (int r = 0; r < 4; ++r) {
                int row = m0 + wr + i * 16 + q * 4 + r;
                float v = acc[i][j][r] + bs;
                if (RELU) v = fmaxf(v, 0.f);
                if (RESID) v += (float)Rsd[(size_t)row * N + col];
                C[(size_t)row * N + col] = (bf16_t)v;
            }
        }
}

// ---------- sparse masked attention: one WAVE per query row ----------
// 4 rows/block. Ballot compaction, register softmax, 12 independent PV chains.
__global__ __launch_bounds__(256) void attn_sparse(const bf16_t* __restrict__ qkv, const int* __restrict__ adj,
                                                   bf16_t* __restrict__ O) {
    __shared__ float s_q[4][D];          // 12 KB
    __shared__ float s_p[4][NH][128];    // 24 KB
    __shared__ int   s_idx[4][128];      // 2 KB

    const int t = threadIdx.x, lane = t & 63, wave = t >> 6;
    const int row = blockIdx.x * 4 + wave;

    // ---- adjacency scan + ballot compaction (wave-private) ----
    const int4* arow = (const int4*)(adj + (size_t)row * S);
    const unsigned long long lower = (1ull << lane) - 1;
    int nacc = 0;
#pragma unroll
    for (int p = 0; p < 8; ++p) {
        int4 v = arow[p * 64 + lane];
        int base = (p * 64 + lane) * 4;
#pragma unroll
        for (int c = 0; c < 4; ++c) {
            int comp = (c == 0) ? v.x : (c == 1) ? v.y : (c == 2) ? v.z : v.w;
            unsigned long long m = __ballot(comp != 0);
            if (comp != 0) {
                int pos = nacc + __popcll(m & lower);
                if (pos < 128) s_idx[wave][pos] = base + c;
            }
            nacc += __popcll(m);
        }
    }
    const int n = (nacc < 128) ? nacc : 128;   // n ~ 21, >= 1 (diag forced)

    // ---- stage q row (f32) ----
#pragma unroll
    for (int c = lane; c < D; c += 64) s_q[wave][c] = (float)qkv[(size_t)row * TD + c];
    __syncthreads();   // publish s_idx / s_q (uniform barrier count for all waves)

    const float* qw = s_q[wave];
    const bool two = (n > 64);                 // wave-uniform

    // ---- scores: lane i handles key s_idx[i] for all 12 heads ----
    float sc0[NH], sc1[NH];
    {
        int j0 = (lane < n) ? s_idx[wave][lane] : -1;
        const bf16_t* kb = qkv + (size_t)(j0 < 0 ? 0 : j0) * TD + D;
#pragma unroll
        for (int h = 0; h < NH; ++h) {
            float dot = 0.f;
            const v8bf* kp = (const v8bf*)(kb + h * HD);
            const float4* qp = (const float4*)(qw + h * HD);
#pragma unroll
            for (int e = 0; e < 8; ++e) {
                v8bf kv = kp[e];
                float4 qa = qp[2 * e], qb = qp[2 * e + 1];
                dot += qa.x * (float)kv[0] + qa.y * (float)kv[1] + qa.z * (float)kv[2] + qa.w * (float)kv[3]
                     + qb.x * (float)kv[4] + qb.y * (float)kv[5] + qb.z * (float)kv[6] + qb.w * (float)kv[7];
            }
            sc0[h] = (j0 >= 0) ? dot * 0.125f : -1e30f;
        }
    }
    if (two) {
        int j1 = (lane + 64 < n) ? s_idx[wave][lane + 64] : -1;
        const bf16_t* kb = qkv + (size_t)(j1 < 0 ? 0 : j1) * TD + D;
#pragma unroll
        for (int h = 0; h < NH; ++h) {
            float dot = 0.f;
            const v8bf* kp = (const v8bf*)(kb + h * HD);
            const float4* qp = (const float4*)(qw + h * HD);
#pragma unroll
            for (int e = 0; e < 8; ++e) {
                v8bf kv = kp[e];
                float4 qa = qp[2 * e], qb = qp[2 * e + 1];
                dot += qa.x * (float)kv[0] + qa.y * (float)kv[1] + qa.z * (float)kv[2] + qa.w * (float)kv[3]
                     + qb.x * (float)kv[4] + qb.y * (float)kv[5] + qb.z * (float)kv[6] + qb.w * (float)kv[7];
            }
            sc1[h] = (j1 >= 0) ? dot * 0.125f : -1e30f;
        }
    } else {
#pragma unroll
        for (int h = 0; h < NH; ++h) sc1[h] = -1e30f;
    }

    // ---- softmax per head (shuffle butterflies, all in registers) ----
#pragma unroll
    for (int h = 0; h < NH; ++h) {
        float m = fmaxf(sc0[h], sc1[h]);
#pragma unroll
        for (int o = 32; o > 0; o >>= 1) m = fmaxf(m, __shfl_xor(m, o, 64));
        float p0 = (lane < n) ? __expf(sc0[h] - m) : 0.f;
        float p1 = (two && lane + 64 < n) ? __expf(sc1[h] - m) : 0.f;
        float sm = p0 + p1;
#pragma unroll
        for (int o = 32; o > 0; o >>= 1) sm += __shfl_xor(sm, o, 64);
        float inv = 1.f / sm;
        s_p[wave][h][lane] = p0 * inv;
        if (two) s_p[wave][h][lane + 64] = p1 * inv;
    }
    __syncthreads();   // publish p (uniform barrier count)

    // ---- PV: lane covers e, 12 independent chains over keys ----
    float acc[NH] = {};
    for (int i = 0; i < n; ++i) {
        int j = s_idx[wave][i];                                  // LDS broadcast
        const bf16_t* vb = qkv + (size_t)j * TD + 2 * D + lane;  // coalesced 128B per h
#pragma unroll
        for (int h = 0; h < NH; ++h)
            acc[h] += s_p[wave][h][i] * (float)vb[h * HD];       // p: LDS broadcast
    }
#pragma unroll
    for (int h = 0; h < NH; ++h)
        O[(size_t)row * D + h * HD + lane] = (bf16_t)acc[h];
}

// ---------- launch ----------
extern "C" void kernel_launch(void* const* d_in, const int* in_sizes, int n_in,
                              void* d_out, int out_size, void* d_ws, size_t ws_size,
                              hipStream_t stream) {
    const float* exp_e = (const float*)d_in[0];
    const float* pert  = (const float*)d_in[1];
    const float* w_in  = (const float*)d_in[2];
    const float* b_in  = (const float*)d_in[3];
    const float* w_out = (const float*)d_in[4];
    const float* b_out = (const float*)d_in[5];
    const float* g0  = (const float*)d_in[6];
    const float* be0 = (const float*)d_in[7];
    const float* g1  = (const float*)d_in[8];
    const float* be1 = (const float*)d_in[9];
    const float* g2  = (const float*)d_in[10];
    const float* be2 = (const float*)d_in[11];
    const float* w1  = (const float*)d_in[12];
    const float* b1  = (const float*)d_in[13];
    const float* w2  = (const float*)d_in[14];
    const float* b2  = (const float*)d_in[15];
    const int*   adj = (const int*)d_in[16];
    float* out = (float*)d_out;

    const size_t SD = (size_t)S * D;
    bf16_t* wb_in  = (bf16_t*)d_ws;               // [2304*768]
    bf16_t* wb_out = wb_in + (size_t)TD * D;      // [768*768]
    bf16_t* wb_1   = wb_out + (size_t)D * D;      // [384*768]
    bf16_t* wb_2   = wb_1 + (size_t)(D / 2) * D;  // [768*384]
    bf16_t* x_in   = wb_2 + (size_t)D * (D / 2);  // [S*D]
    bf16_t* qkv    = x_in + SD;                   // [S*3D]
    bf16_t* attn_o = qkv + 3 * SD;                // [S*D]
    bf16_t* y1     = attn_o + SD;                 // [S*D] pre-LN1
    bf16_t* x1     = y1 + SD;                     // [S*D] ln1 out
    bf16_t* ffh    = x1 + SD;                     // [S*D/2]
    bf16_t* y2     = ffh + SD / 2;                // [S*D] pre-LN2

    const int NW = NW0 + NW1 + NW2 + NW3;
    cvt_all<<<(NW + 255) / 256, 256, 0, stream>>>(w_in, w_out, w1, w2, wb_in, wb_out, wb_1, wb_2);
    add_ln<<<S, 256, 0, stream>>>(exp_e, pert, g0, be0, x_in);
    gemm_mfma<64, 128, 0, false><<<dim3(TD / 128, S / 64), 256, 0, stream>>>(x_in, wb_in, b_in, nullptr, qkv, S, TD, D);
    attn_sparse<<<S / 4, 256, 0, stream>>>(qkv, adj, attn_o);
    gemm_mfma<32, 64, 0, true><<<dim3(D / 64, S / 32), 256, 0, stream>>>(attn_o, wb_out, b_out, x_in, y1, S, D, D);
    ln_only<bf16_t><<<S, 256, 0, stream>>>(y1, g1, be1, x1);
    gemm_mfma<32, 32, 1, false><<<dim3((D / 2) / 32, S / 32), 256, 0, stream>>>(x1, wb_1, b1, nullptr, ffh, S, D / 2, D);
    gemm_mfma<32, 64, 0, true><<<dim3(D / 64, S / 32), 256, 0, stream>>>(ffh, wb_2, b2, x1, y2, S, D, D / 2);
    ln_only<float><<<S, 256, 0, stream>>>(y2, g2, be2, out);
}

// Round 6
// 202.681 us; speedup vs baseline: 1.8538x; 1.8538x over previous
//
#include <hip/hip_runtime.h>

#define S 2048
#define D 768
#define NH 12
#define HD 64
#define TD (3 * D)

typedef __bf16 bf16_t;
typedef __bf16 v8bf __attribute__((ext_vector_type(8)));
typedef __bf16 v4bf __attribute__((ext_vector_type(4)));
typedef float v4f __attribute__((ext_vector_type(4)));

// ---------- reductions ----------
__device__ __forceinline__ float wave_reduce_sum(float v) {
#pragma unroll
    for (int o = 32; o > 0; o >>= 1) v += __shfl_down(v, o, 64);
    return v;
}
__device__ __forceinline__ float wave_reduce_max(float v) {
#pragma unroll
    for (int o = 32; o > 0; o >>= 1) v = fmaxf(v, __shfl_down(v, o, 64));
    return v;
}
__device__ float block_reduce_sum(float v) {
    __shared__ float t4[4];
    int lane = threadIdx.x & 63, wid = threadIdx.x >> 6;
    v = wave_reduce_sum(v);
    __syncthreads();
    if (lane == 0) t4[wid] = v;
    __syncthreads();
    return t4[0] + t4[1] + t4[2] + t4[3];
}
__device__ float block_reduce_max(float v) {
    __shared__ float t4m[4];
    int lane = threadIdx.x & 63, wid = threadIdx.x >> 6;
    v = wave_reduce_max(v);
    __syncthreads();
    if (lane == 0) t4m[wid] = v;
    __syncthreads();
    return fmaxf(fmaxf(t4m[0], t4m[1]), fmaxf(t4m[2], t4m[3]));
}

// ---------- fused residual-add + LayerNorm (ln0: two fp32 inputs) ----------
__global__ __launch_bounds__(256) void add_ln(const float* __restrict__ A, const float* __restrict__ Bv,
                                              const float* __restrict__ g, const float* __restrict__ be,
                                              bf16_t* __restrict__ out) {
    int row = blockIdx.x, t = threadIdx.x;
    const float* a = A + (size_t)row * D;
    const float* b = Bv + (size_t)row * D;
    float x[3];
    float s = 0.f;
#pragma unroll
    for (int i = 0; i < 3; ++i) { int c = t + 256 * i; x[i] = a[c] + b[c]; s += x[i]; }
    float mean = block_reduce_sum(s) * (1.0f / D);
    float vs = 0.f;
#pragma unroll
    for (int i = 0; i < 3; ++i) { float d = x[i] - mean; vs += d * d; }
    float var = block_reduce_sum(vs) * (1.0f / D);
    float rstd = rsqrtf(var + 1e-5f);
#pragma unroll
    for (int i = 0; i < 3; ++i) {
        int c = t + 256 * i;
        out[(size_t)row * D + c] = (bf16_t)((x[i] - mean) * rstd * g[c] + be[c]);
    }
}

// ---------- single-input LayerNorm ----------
template <typename TO>
__global__ __launch_bounds__(256) void ln_only(const bf16_t* __restrict__ X,
                                               const float* __restrict__ g, const float* __restrict__ be,
                                               TO* __restrict__ out) {
    int row = blockIdx.x, t = threadIdx.x;
    const bf16_t* a = X + (size_t)row * D;
    float x[3];
    float s = 0.f;
#pragma unroll
    for (int i = 0; i < 3; ++i) { int c = t + 256 * i; x[i] = (float)a[c]; s += x[i]; }
    float mean = block_reduce_sum(s) * (1.0f / D);
    float vs = 0.f;
#pragma unroll
    for (int i = 0; i < 3; ++i) { float d = x[i] - mean; vs += d * d; }
    float var = block_reduce_sum(vs) * (1.0f / D);
    float rstd = rsqrtf(var + 1e-5f);
#pragma unroll
    for (int i = 0; i < 3; ++i) {
        int c = t + 256 * i;
        out[(size_t)row * D + c] = (TO)((x[i] - mean) * rstd * g[c] + be[c]);
    }
}

// ---------- fused fp32 -> bf16 conversion of all 4 weight matrices ----------
#define NW0 (TD * D / 4)
#define NW1 (D * D / 4)
#define NW2 ((D / 2) * D / 4)
#define NW3 (D * (D / 2) / 4)
__global__ __launch_bounds__(256) void cvt_all(const float* __restrict__ s0, const float* __restrict__ s1,
                                               const float* __restrict__ s2, const float* __restrict__ s3,
                                               bf16_t* __restrict__ d0, bf16_t* __restrict__ d1,
                                               bf16_t* __restrict__ d2, bf16_t* __restrict__ d3) {
    int i = blockIdx.x * 256 + threadIdx.x;
    const float* sp; bf16_t* dp;
    if (i < NW0) { sp = s0; dp = d0; }
    else if (i < NW0 + NW1) { sp = s1; dp = d1; i -= NW0; }
    else if (i < NW0 + NW1 + NW2) { sp = s2; dp = d2; i -= NW0 + NW1; }
    else if (i < NW0 + NW1 + NW2 + NW3) { sp = s3; dp = d3; i -= NW0 + NW1 + NW2; }
    else return;
    float4 v = ((const float4*)sp)[i];
    v4bf o = {(bf16_t)v.x, (bf16_t)v.y, (bf16_t)v.z, (bf16_t)v.w};
    *(v4bf*)(dp + (size_t)i * 4) = o;
}

// ---------- MFMA GEMM: C[M,N] = act(A[M,K] @ B[N,K]^T + bias[N]) [+ Rsd] ----------
// TM x TN tile, BK=32, 256 threads as 2x2 waves. global_load_lds width-16 staging.
#define GBK 32

template <int TM, int TN, int RELU, bool RESID>
__global__ __launch_bounds__(256) void gemm_mfma(const bf16_t* __restrict__ A, const bf16_t* __restrict__ B,
                                                 const float* __restrict__ bias,
                                                 const bf16_t* __restrict__ Rsd, bf16_t* __restrict__ C,
                                                 int M, int N, int K) {
    constexpr int CA = TM * 4;                 // A chunks (16 B each, 4 per row)
    constexpr int CHUNKS = (TM + TN) * 4;
    constexpr int P = (CHUNKS + 255) / 256;
    constexpr int MI = TM / 32, NI = TN / 32;
    __shared__ bf16_t As[TM * GBK];
    __shared__ bf16_t Bs[TN * GBK];
    const int t = threadIdx.x;
    const int lane = t & 63, wave = t >> 6;
    const int wr = (wave >> 1) * (TM / 2), wc = (wave & 1) * (TN / 2);
    const int m0 = blockIdx.y * TM, n0 = blockIdx.x * TN;
    const int lm = lane & 15, q = lane >> 4;

    const bf16_t* gsrc[P];
    bf16_t* ldst[P];
    bool act[P];
#pragma unroll
    for (int p = 0; p < P; ++p) {
        int c = t + 256 * p;
        act[p] = (c < CHUNKS);
        int cc = (c < CA) ? c : c - CA;
        int row = cc >> 2, col = (cc & 3) * 8;
        if (c < CA) { gsrc[p] = A + (size_t)(m0 + row) * K + col; ldst[p] = As + cc * 8; }
        else        { gsrc[p] = B + (size_t)(n0 + row) * K + col; ldst[p] = Bs + cc * 8; }
    }

    v4f acc[MI][NI] = {};

    for (int k0 = 0; k0 < K; k0 += GBK) {
#pragma unroll
        for (int p = 0; p < P; ++p)
            if (act[p])
                __builtin_amdgcn_global_load_lds((const __attribute__((address_space(1))) void*)(gsrc[p] + k0),
                                                 (__attribute__((address_space(3))) void*)ldst[p], 16, 0, 0);
        __syncthreads();  // drains vmcnt -> staged data visible

        v8bf af[MI], bfr[NI];
#pragma unroll
        for (int i = 0; i < MI; ++i) af[i] = *(const v8bf*)(As + (wr + i * 16 + lm) * GBK + q * 8);
#pragma unroll
        for (int j = 0; j < NI; ++j) bfr[j] = *(const v8bf*)(Bs + (wc + j * 16 + lm) * GBK + q * 8);
#pragma unroll
        for (int i = 0; i < MI; ++i)
#pragma unroll
            for (int j = 0; j < NI; ++j)
                acc[i][j] = __builtin_amdgcn_mfma_f32_16x16x32_bf16(af[i], bfr[j], acc[i][j], 0, 0, 0);
        __syncthreads();
    }

    // D mapping (verified m89/m91): row = quad*4 + reg, col = lane&15
#pragma unroll
    for (int i = 0; i < MI; ++i)
#pragma unroll
        for (int j = 0; j < NI; ++j) {
            int col = n0 + wc + j * 16 + lm;
            float bs = bias[col];
#pragma unroll
            for (int r = 0; r < 4; ++r) {
                int row = m0 + wr + i * 16 + q * 4 + r;
                float v = acc[i][j][r] + bs;
                if (RELU) v = fmaxf(v, 0.f);
                if (RESID) v += (float)Rsd[(size_t)row * N + col];
                C[(size_t)row * N + col] = (bf16_t)v;
            }
        }
}

// ---------- sparse masked attention (block per row; conflict-free score mapping) ----------
__global__ __launch_bounds__(256) void attn_sparse(const bf16_t* __restrict__ qkv, const int* __restrict__ adj,
                                                   bf16_t* __restrict__ O) {
    __shared__ int s_idx[128];
    __shared__ int s_cnt;
    __shared__ float s_q[D];
    __shared__ float s_p[NH][128];

    const int row = blockIdx.x, t = threadIdx.x;
    const int lane = t & 63, wave = t >> 6;
    if (t == 0) s_cnt = 0;
    __syncthreads();

    // adjacency scan, int4-vectorized
    const int4* arow = (const int4*)(adj + (size_t)row * S);
#pragma unroll
    for (int p = 0; p < 2; ++p) {
        int4 v = arow[t + 256 * p];
        int base = (t + 256 * p) * 4;
        if (v.x) { int k = atomicAdd(&s_cnt, 1); if (k < 128) s_idx[k] = base + 0; }
        if (v.y) { int k = atomicAdd(&s_cnt, 1); if (k < 128) s_idx[k] = base + 1; }
        if (v.z) { int k = atomicAdd(&s_cnt, 1); if (k < 128) s_idx[k] = base + 2; }
        if (v.w) { int k = atomicAdd(&s_cnt, 1); if (k < 128) s_idx[k] = base + 3; }
    }
    for (int c = t; c < D; c += 256) s_q[c] = (float)qkv[(size_t)row * TD + c];
    __syncthreads();
    const int n = (s_cnt < 128) ? s_cnt : 128;  // n ~ 21, >= 1 (diag forced)

    // scores: n*12 items; mapping h = it/n, i = it%n so consecutive threads
    // write consecutive s_p[h][i] (bank-conflict-free; was 12-way with h=it%NH)
    for (int it = t; it < n * NH; it += 256) {
        int h = it / n, i = it - h * n;
        int j = s_idx[i];
        const bf16_t* kp = qkv + (size_t)j * TD + D + h * HD;
        const float* qp = s_q + h * HD;
        float dot = 0.f;
#pragma unroll
        for (int c = 0; c < HD; c += 8) {
            v8bf kv = *(const v8bf*)(kp + c);
#pragma unroll
            for (int e = 0; e < 8; ++e) dot += qp[c + e] * (float)kv[e];
        }
        s_p[h][i] = dot * 0.125f;  // 1/sqrt(64)
    }
    __syncthreads();

    // softmax: 3 heads per wave, shuffle butterflies
    for (int h = wave; h < NH; h += 4) {
        float v0 = (lane < n) ? s_p[h][lane] : -1e30f;
        float v1 = (lane + 64 < n) ? s_p[h][lane + 64] : -1e30f;
        float m = fmaxf(v0, v1);
#pragma unroll
        for (int o = 32; o > 0; o >>= 1) m = fmaxf(m, __shfl_xor(m, o, 64));
        float p0 = (lane < n) ? __expf(v0 - m) : 0.f;
        float p1 = (lane + 64 < n) ? __expf(v1 - m) : 0.f;
        float sm = p0 + p1;
#pragma unroll
        for (int o = 32; o > 0; o >>= 1) sm += __shfl_xor(sm, o, 64);
        float inv = 1.f / sm;
        if (lane < n) s_p[h][lane] = p0 * inv;
        if (lane + 64 < n) s_p[h][lane + 64] = p1 * inv;
    }
    __syncthreads();

    // PV: all 768 (h,e) outputs in parallel (3 per thread); p reads broadcast
    for (int o = t; o < D; o += 256) {
        int h = o >> 6, e = o & 63;
        const float* pp = s_p[h];
        float acc = 0.f;
        for (int i = 0; i < n; ++i)
            acc += pp[i] * (float)qkv[(size_t)s_idx[i] * TD + 2 * D + h * HD + e];
        O[(size_t)row * D + o] = (bf16_t)acc;
    }
}

// ---------- launch ----------
extern "C" void kernel_launch(void* const* d_in, const int* in_sizes, int n_in,
                              void* d_out, int out_size, void* d_ws, size_t ws_size,
                              hipStream_t stream) {
    const float* exp_e = (const float*)d_in[0];
    const float* pert  = (const float*)d_in[1];
    const float* w_in  = (const float*)d_in[2];
    const float* b_in  = (const float*)d_in[3];
    const float* w_out = (const float*)d_in[4];
    const float* b_out = (const float*)d_in[5];
    const float* g0  = (const float*)d_in[6];
    const float* be0 = (const float*)d_in[7];
    const float* g1  = (const float*)d_in[8];
    const float* be1 = (const float*)d_in[9];
    const float* g2  = (const float*)d_in[10];
    const float* be2 = (const float*)d_in[11];
    const float* w1  = (const float*)d_in[12];
    const float* b1  = (const float*)d_in[13];
    const float* w2  = (const float*)d_in[14];
    const float* b2  = (const float*)d_in[15];
    const int*   adj = (const int*)d_in[16];
    float* out = (float*)d_out;

    const size_t SD = (size_t)S * D;
    bf16_t* wb_in  = (bf16_t*)d_ws;               // [2304*768]
    bf16_t* wb_out = wb_in + (size_t)TD * D;      // [768*768]
    bf16_t* wb_1   = wb_out + (size_t)D * D;      // [384*768]
    bf16_t* wb_2   = wb_1 + (size_t)(D / 2) * D;  // [768*384]
    bf16_t* x_in   = wb_2 + (size_t)D * (D / 2);  // [S*D]
    bf16_t* qkv    = x_in + SD;                   // [S*3D]
    bf16_t* attn_o = qkv + 3 * SD;                // [S*D]
    bf16_t* y1     = attn_o + SD;                 // [S*D] pre-LN1
    bf16_t* x1     = y1 + SD;                     // [S*D] ln1 out
    bf16_t* ffh    = x1 + SD;                     // [S*D/2]
    bf16_t* y2     = ffh + SD / 2;                // [S*D] pre-LN2

    const int NW = NW0 + NW1 + NW2 + NW3;
    cvt_all<<<(NW + 255) / 256, 256, 0, stream>>>(w_in, w_out, w1, w2, wb_in, wb_out, wb_1, wb_2);
    add_ln<<<S, 256, 0, stream>>>(exp_e, pert, g0, be0, x_in);
    gemm_mfma<64, 128, 0, false><<<dim3(TD / 128, S / 64), 256, 0, stream>>>(x_in, wb_in, b_in, nullptr, qkv, S, TD, D);
    attn_sparse<<<S, 256, 0, stream>>>(qkv, adj, attn_o);
    gemm_mfma<32, 64, 0, true><<<dim3(D / 64, S / 32), 256, 0, stream>>>(attn_o, wb_out, b_out, x_in, y1, S, D, D);
    ln_only<bf16_t><<<S, 256, 0, stream>>>(y1, g1, be1, x1);
    gemm_mfma<32, 32, 1, false><<<dim3((D / 2) / 32, S / 32), 256, 0, stream>>>(x1, wb_1, b1, nullptr, ffh, S, D / 2, D);
    gemm_mfma<32, 64, 0, true><<<dim3(D / 64, S / 32), 256, 0, stream>>>(ffh, wb_2, b2, x1, y2, S, D, D / 2);
    ln_only<float><<<S, 256, 0, stream>>>(y2, g2, be2, out);
}

// Round 7
// 196.304 us; speedup vs baseline: 1.9140x; 1.0325x over previous
//
#include <hip/hip_runtime.h>

#define S 2048
#define D 768
#define NH 12
#define HD 64
#define TD (3 * D)

typedef __bf16 bf16_t;
typedef __bf16 v8bf __attribute__((ext_vector_type(8)));
typedef __bf16 v4bf __attribute__((ext_vector_type(4)));
typedef float v4f __attribute__((ext_vector_type(4)));

// ---------- reductions ----------
__device__ __forceinline__ float wave_reduce_sum(float v) {
#pragma unroll
    for (int o = 32; o > 0; o >>= 1) v += __shfl_down(v, o, 64);
    return v;
}
__device__ float block_reduce_sum(float v) {
    __shared__ float t4[4];
    int lane = threadIdx.x & 63, wid = threadIdx.x >> 6;
    v = wave_reduce_sum(v);
    __syncthreads();
    if (lane == 0) t4[wid] = v;
    __syncthreads();
    return t4[0] + t4[1] + t4[2] + t4[3];
}

// ---------- fused: blocks [0,S) do add+LN; blocks [S, S+2880) convert weights ----------
#define NW0 (TD * D / 4)
#define NW1 (D * D / 4)
#define NW2 ((D / 2) * D / 4)
#define NW3 (D * (D / 2) / 4)
#define NWALL (NW0 + NW1 + NW2 + NW3)

__global__ __launch_bounds__(256) void addln_cvt(const float* __restrict__ A, const float* __restrict__ Bv,
                                                 const float* __restrict__ g, const float* __restrict__ be,
                                                 bf16_t* __restrict__ out,
                                                 const float* __restrict__ s0, const float* __restrict__ s1,
                                                 const float* __restrict__ s2, const float* __restrict__ s3,
                                                 bf16_t* __restrict__ d0, bf16_t* __restrict__ d1,
                                                 bf16_t* __restrict__ d2, bf16_t* __restrict__ d3) {
    int blk = blockIdx.x, t = threadIdx.x;
    if (blk >= S) {
        int i = (blk - S) * 256 + t;
        const float* sp; bf16_t* dp;
        if (i < NW0) { sp = s0; dp = d0; }
        else if (i < NW0 + NW1) { sp = s1; dp = d1; i -= NW0; }
        else if (i < NW0 + NW1 + NW2) { sp = s2; dp = d2; i -= NW0 + NW1; }
        else if (i < NWALL) { sp = s3; dp = d3; i -= NW0 + NW1 + NW2; }
        else return;
        float4 v = ((const float4*)sp)[i];
        v4bf o = {(bf16_t)v.x, (bf16_t)v.y, (bf16_t)v.z, (bf16_t)v.w};
        *(v4bf*)(dp + (size_t)i * 4) = o;
        return;
    }
    int row = blk;
    const float* a = A + (size_t)row * D;
    const float* b = Bv + (size_t)row * D;
    float x[3];
    float s = 0.f;
#pragma unroll
    for (int i = 0; i < 3; ++i) { int c = t + 256 * i; x[i] = a[c] + b[c]; s += x[i]; }
    float mean = block_reduce_sum(s) * (1.0f / D);
    float vs = 0.f;
#pragma unroll
    for (int i = 0; i < 3; ++i) { float d = x[i] - mean; vs += d * d; }
    float var = block_reduce_sum(vs) * (1.0f / D);
    float rstd = rsqrtf(var + 1e-5f);
#pragma unroll
    for (int i = 0; i < 3; ++i) {
        int c = t + 256 * i;
        out[(size_t)row * D + c] = (bf16_t)((x[i] - mean) * rstd * g[c] + be[c]);
    }
}

// ---------- single-input LayerNorm ----------
template <typename TO>
__global__ __launch_bounds__(256) void ln_only(const bf16_t* __restrict__ X,
                                               const float* __restrict__ g, const float* __restrict__ be,
                                               TO* __restrict__ out) {
    int row = blockIdx.x, t = threadIdx.x;
    const bf16_t* a = X + (size_t)row * D;
    float x[3];
    float s = 0.f;
#pragma unroll
    for (int i = 0; i < 3; ++i) { int c = t + 256 * i; x[i] = (float)a[c]; s += x[i]; }
    float mean = block_reduce_sum(s) * (1.0f / D);
    float vs = 0.f;
#pragma unroll
    for (int i = 0; i < 3; ++i) { float d = x[i] - mean; vs += d * d; }
    float var = block_reduce_sum(vs) * (1.0f / D);
    float rstd = rsqrtf(var + 1e-5f);
#pragma unroll
    for (int i = 0; i < 3; ++i) {
        int c = t + 256 * i;
        out[(size_t)row * D + c] = (TO)((x[i] - mean) * rstd * g[c] + be[c]);
    }
}

// ---------- MFMA GEMM: C[M,N] = act(A[M,K] @ B[N,K]^T + bias[N]) [+ Rsd] ----------
// BK=64 as two 32-slabs (slab-major LDS): one barrier pair per 64-deep K step,
// LDS fragment addressing identical to the proven BK=32 layout. global_load_lds
// width-16 staging; chunk mapping stays lane-contiguous (wave-uniform base +
// lane*16) because ldst is affine-contiguous in chunk id.
#define GBK 64

template <int TM, int TN, int RELU, bool RESID>
__global__ __launch_bounds__(256) void gemm_mfma(const bf16_t* __restrict__ A, const bf16_t* __restrict__ B,
                                                 const float* __restrict__ bias,
                                                 const bf16_t* __restrict__ Rsd, bf16_t* __restrict__ C,
                                                 int M, int N, int K) {
    constexpr int CA = TM * 8;                  // A chunks (16 B): 2 slabs * TM rows * 4
    constexpr int CHUNKS = (TM + TN) * 8;
    constexpr int P = CHUNKS / 256;
    static_assert(CHUNKS % 256 == 0, "chunk passes must be exact");
    constexpr int MI = TM / 32, NI = TN / 32;
    __shared__ bf16_t As[TM * GBK];
    __shared__ bf16_t Bs[TN * GBK];
    const int t = threadIdx.x;
    const int lane = t & 63, wave = t >> 6;
    const int wr = (wave >> 1) * (TM / 2), wc = (wave & 1) * (TN / 2);
    const int m0 = blockIdx.y * TM, n0 = blockIdx.x * TN;
    const int lm = lane & 15, q = lane >> 4;

    const bf16_t* gsrc[P];
    bf16_t* ldst[P];
#pragma unroll
    for (int p = 0; p < P; ++p) {
        int c = t + 256 * p;
        if (c < CA) {
            int slab = c / (TM * 4), r4 = c % (TM * 4);
            int row = r4 >> 2, c4 = r4 & 3;
            gsrc[p] = A + (size_t)(m0 + row) * K + slab * 32 + c4 * 8;
            ldst[p] = As + slab * (TM * 32) + row * 32 + c4 * 8;
        } else {
            int cc = c - CA;
            int slab = cc / (TN * 4), r4 = cc % (TN * 4);
            int row = r4 >> 2, c4 = r4 & 3;
            gsrc[p] = B + (size_t)(n0 + row) * K + slab * 32 + c4 * 8;
            ldst[p] = Bs + slab * (TN * 32) + row * 32 + c4 * 8;
        }
    }

    v4f acc[MI][NI] = {};

    for (int k0 = 0; k0 < K; k0 += GBK) {
#pragma unroll
        for (int p = 0; p < P; ++p)
            __builtin_amdgcn_global_load_lds((const __attribute__((address_space(1))) void*)(gsrc[p] + k0),
                                             (__attribute__((address_space(3))) void*)ldst[p], 16, 0, 0);
        __syncthreads();  // drains vmcnt -> staged data visible

        v8bf af[2][MI], bfr[2][NI];
#pragma unroll
        for (int s = 0; s < 2; ++s) {
#pragma unroll
            for (int i = 0; i < MI; ++i)
                af[s][i] = *(const v8bf*)(As + s * (TM * 32) + (wr + i * 16 + lm) * 32 + q * 8);
#pragma unroll
            for (int j = 0; j < NI; ++j)
                bfr[s][j] = *(const v8bf*)(Bs + s * (TN * 32) + (wc + j * 16 + lm) * 32 + q * 8);
        }
#pragma unroll
        for (int s = 0; s < 2; ++s)
#pragma unroll
            for (int i = 0; i < MI; ++i)
#pragma unroll
                for (int j = 0; j < NI; ++j)
                    acc[i][j] = __builtin_amdgcn_mfma_f32_16x16x32_bf16(af[s][i], bfr[s][j], acc[i][j], 0, 0, 0);
        __syncthreads();
    }

    // D mapping (verified m89/m91): row = quad*4 + reg, col = lane&15
#pragma unroll
    for (int i = 0; i < MI; ++i)
#pragma unroll
        for (int j = 0; j < NI; ++j) {
            int col = n0 + wc + j * 16 + lm;
            float bs = bias[col];
#pragma unroll
            for (int r = 0; r < 4; ++r) {
                int row = m0 + wr + i * 16 + q * 4 + r;
                float v = acc[i][j][r] + bs;
                if (RELU) v = fmaxf(v, 0.f);
                if (RESID) v += (float)Rsd[(size_t)row * N + col];
                C[(size_t)row * N + col] = (bf16_t)v;
            }
        }
}

// ---------- sparse masked attention (block per row; conflict-free score mapping) ----------
__global__ __launch_bounds__(256) void attn_sparse(const bf16_t* __restrict__ qkv, const int* __restrict__ adj,
                                                   bf16_t* __restrict__ O) {
    __shared__ int s_idx[128];
    __shared__ int s_cnt;
    __shared__ float s_q[D];
    __shared__ float s_p[NH][128];

    const int row = blockIdx.x, t = threadIdx.x;
    const int lane = t & 63, wave = t >> 6;
    if (t == 0) s_cnt = 0;
    __syncthreads();

    const int4* arow = (const int4*)(adj + (size_t)row * S);
#pragma unroll
    for (int p = 0; p < 2; ++p) {
        int4 v = arow[t + 256 * p];
        int base = (t + 256 * p) * 4;
        if (v.x) { int k = atomicAdd(&s_cnt, 1); if (k < 128) s_idx[k] = base + 0; }
        if (v.y) { int k = atomicAdd(&s_cnt, 1); if (k < 128) s_idx[k] = base + 1; }
        if (v.z) { int k = atomicAdd(&s_cnt, 1); if (k < 128) s_idx[k] = base + 2; }
        if (v.w) { int k = atomicAdd(&s_cnt, 1); if (k < 128) s_idx[k] = base + 3; }
    }
    for (int c = t; c < D; c += 256) s_q[c] = (float)qkv[(size_t)row * TD + c];
    __syncthreads();
    const int n = (s_cnt < 128) ? s_cnt : 128;  // n ~ 21, >= 1 (diag forced)

    // scores: h = it/n, i = it%n -> consecutive threads hit consecutive s_p[h][i]
    for (int it = t; it < n * NH; it += 256) {
        int h = it / n, i = it - h * n;
        int j = s_idx[i];
        const bf16_t* kp = qkv + (size_t)j * TD + D + h * HD;
        const float* qp = s_q + h * HD;
        float dot = 0.f;
#pragma unroll
        for (int c = 0; c < HD; c += 8) {
            v8bf kv = *(const v8bf*)(kp + c);
#pragma unroll
            for (int e = 0; e < 8; ++e) dot += qp[c + e] * (float)kv[e];
        }
        s_p[h][i] = dot * 0.125f;  // 1/sqrt(64)
    }
    __syncthreads();

    // softmax: 3 heads per wave, shuffle butterflies
    for (int h = wave; h < NH; h += 4) {
        float v0 = (lane < n) ? s_p[h][lane] : -1e30f;
        float v1 = (lane + 64 < n) ? s_p[h][lane + 64] : -1e30f;
        float m = fmaxf(v0, v1);
#pragma unroll
        for (int o = 32; o > 0; o >>= 1) m = fmaxf(m, __shfl_xor(m, o, 64));
        float p0 = (lane < n) ? __expf(v0 - m) : 0.f;
        float p1 = (lane + 64 < n) ? __expf(v1 - m) : 0.f;
        float sm = p0 + p1;
#pragma unroll
        for (int o = 32; o > 0; o >>= 1) sm += __shfl_xor(sm, o, 64);
        float inv = 1.f / sm;
        if (lane < n) s_p[h][lane] = p0 * inv;
        if (lane + 64 < n) s_p[h][lane + 64] = p1 * inv;
    }
    __syncthreads();

    // PV: 768 (h,e) outputs, 3 per thread; coalesced V lines, broadcast p
    for (int o = t; o < D; o += 256) {
        int h = o >> 6, e = o & 63;
        const float* pp = s_p[h];
        float acc = 0.f;
        for (int i = 0; i < n; ++i)
            acc += pp[i] * (float)qkv[(size_t)s_idx[i] * TD + 2 * D + h * HD + e];
        O[(size_t)row * D + o] = (bf16_t)acc;
    }
}

// ---------- launch ----------
extern "C" void kernel_launch(void* const* d_in, const int* in_sizes, int n_in,
                              void* d_out, int out_size, void* d_ws, size_t ws_size,
                              hipStream_t stream) {
    const float* exp_e = (const float*)d_in[0];
    const float* pert  = (const float*)d_in[1];
    const float* w_in  = (const float*)d_in[2];
    const float* b_in  = (const float*)d_in[3];
    const float* w_out = (const float*)d_in[4];
    const float* b_out = (const float*)d_in[5];
    const float* g0  = (const float*)d_in[6];
    const float* be0 = (const float*)d_in[7];
    const float* g1  = (const float*)d_in[8];
    const float* be1 = (const float*)d_in[9];
    const float* g2  = (const float*)d_in[10];
    const float* be2 = (const float*)d_in[11];
    const float* w1  = (const float*)d_in[12];
    const float* b1  = (const float*)d_in[13];
    const float* w2  = (const float*)d_in[14];
    const float* b2  = (const float*)d_in[15];
    const int*   adj = (const int*)d_in[16];
    float* out = (float*)d_out;

    const size_t SD = (size_t)S * D;
    bf16_t* wb_in  = (bf16_t*)d_ws;               // [2304*768]
    bf16_t* wb_out = wb_in + (size_t)TD * D;      // [768*768]
    bf16_t* wb_1   = wb_out + (size_t)D * D;      // [384*768]
    bf16_t* wb_2   = wb_1 + (size_t)(D / 2) * D;  // [768*384]
    bf16_t* x_in   = wb_2 + (size_t)D * (D / 2);  // [S*D]
    bf16_t* qkv    = x_in + SD;                   // [S*3D]
    bf16_t* attn_o = qkv + 3 * SD;                // [S*D]
    bf16_t* y1     = attn_o + SD;                 // [S*D] pre-LN1
    bf16_t* x1     = y1 + SD;                     // [S*D] ln1 out
    bf16_t* ffh    = x1 + SD;                     // [S*D/2]
    bf16_t* y2     = ffh + SD / 2;                // [S*D] pre-LN2

    const int CVTB = (NWALL + 255) / 256;
    addln_cvt<<<S + CVTB, 256, 0, stream>>>(exp_e, pert, g0, be0, x_in,
                                            w_in, w_out, w1, w2, wb_in, wb_out, wb_1, wb_2);
    gemm_mfma<64, 128, 0, false><<<dim3(TD / 128, S / 64), 256, 0, stream>>>(x_in, wb_in, b_in, nullptr, qkv, S, TD, D);
    attn_sparse<<<S, 256, 0, stream>>>(qkv, adj, attn_o);
    gemm_mfma<64, 64, 0, true><<<dim3(D / 64, S / 64), 256, 0, stream>>>(attn_o, wb_out, b_out, x_in, y1, S, D, D);
    ln_only<bf16_t><<<S, 256, 0, stream>>>(y1, g1, be1, x1);
    gemm_mfma<32, 64, 1, false><<<dim3((D / 2) / 64, S / 32), 256, 0, stream>>>(x1, wb_1, b1, nullptr, ffh, S, D / 2, D);
    gemm_mfma<64, 64, 0, true><<<dim3(D / 64, S / 64), 256, 0, stream>>>(ffh, wb_2, b2, x1, y2, S, D, D / 2);
    ln_only<float><<<S, 256, 0, stream>>>(y2, g2, be2, out);
}